// Round 1
// baseline (219.280 us; speedup 1.0000x reference)
//
#include <hip/hip_runtime.h>
#include <math.h>

#define BB 64
#define NN 2048
#define DZ 128
#define DA 64
#define DD 192
#define EE 16
#define HH 512
#define LN_EPS 1e-5f

__device__ __forceinline__ float mishf(float x) {
    float sp = (x > 20.f) ? x : log1pf(__expf(x));
    return x * tanhf(sp);
}

// K1: weights[b,n,e] = sum_d x[b,n,d] * phi[d,e]
__global__ __launch_bounds__(256)
void k_weights(const float* __restrict__ z, const float* __restrict__ a,
               const float* __restrict__ phi, float* __restrict__ w) {
    __shared__ float phis[DD * EE];
    int t = threadIdx.x;
    for (int i = t; i < DD * EE; i += 256) phis[i] = phi[i];
    __syncthreads();

    long token = (long)blockIdx.x * 256 + t;   // 0 .. B*N-1
    int b = (int)(token >> 11);
    int n = (int)(token & (NN - 1));

    const float4* zr = (const float4*)(z + ((long)b * NN + n) * DZ);
    const float4* ar = (const float4*)(a + ((long)b * NN + n) * DA);

    float acc[EE];
#pragma unroll
    for (int e = 0; e < EE; e++) acc[e] = 0.f;

#pragma unroll 4
    for (int q = 0; q < DZ / 4; q++) {
        float4 v = zr[q];
        const float* pv = &v.x;
#pragma unroll
        for (int c = 0; c < 4; c++) {
            float xv = pv[c];
            const float4* pr = (const float4*)(phis + (q * 4 + c) * EE);
#pragma unroll
            for (int e4 = 0; e4 < 4; e4++) {
                float4 p = pr[e4];
                acc[e4 * 4 + 0] += xv * p.x;
                acc[e4 * 4 + 1] += xv * p.y;
                acc[e4 * 4 + 2] += xv * p.z;
                acc[e4 * 4 + 3] += xv * p.w;
            }
        }
    }
#pragma unroll 4
    for (int q = 0; q < DA / 4; q++) {
        float4 v = ar[q];
        const float* pv = &v.x;
#pragma unroll
        for (int c = 0; c < 4; c++) {
            float xv = pv[c];
            const float4* pr = (const float4*)(phis + (DZ + q * 4 + c) * EE);
#pragma unroll
            for (int e4 = 0; e4 < 4; e4++) {
                float4 p = pr[e4];
                acc[e4 * 4 + 0] += xv * p.x;
                acc[e4 * 4 + 1] += xv * p.y;
                acc[e4 * 4 + 2] += xv * p.z;
                acc[e4 * 4 + 3] += xv * p.w;
            }
        }
    }

    float4* wout = (float4*)(w + token * EE);
#pragma unroll
    for (int e4 = 0; e4 < 4; e4++)
        wout[e4] = make_float4(acc[e4 * 4 + 0], acc[e4 * 4 + 1],
                               acc[e4 * 4 + 2], acc[e4 * 4 + 3]);
}

// K2: per (b,e): max over n and 1/sum(exp(w-max)) over n
#define RSTR 17
__global__ __launch_bounds__(256)
void k_stats(const float* __restrict__ w, float* __restrict__ gmax,
             float* __restrict__ grcp) {
    __shared__ float red[256 * RSTR];
    int b = blockIdx.x, t = threadIdx.x;
    const float* wb = w + (long)b * NN * EE;

    float m[EE];
#pragma unroll
    for (int e = 0; e < EE; e++) m[e] = -1e30f;
    for (int k = 0; k < NN / 256; k++) {
        const float4* row = (const float4*)(wb + ((long)(k * 256 + t)) * EE);
#pragma unroll
        for (int q = 0; q < 4; q++) {
            float4 v = row[q];
            m[q * 4 + 0] = fmaxf(m[q * 4 + 0], v.x);
            m[q * 4 + 1] = fmaxf(m[q * 4 + 1], v.y);
            m[q * 4 + 2] = fmaxf(m[q * 4 + 2], v.z);
            m[q * 4 + 3] = fmaxf(m[q * 4 + 3], v.w);
        }
    }
#pragma unroll
    for (int e = 0; e < EE; e++) red[t * RSTR + e] = m[e];
    __syncthreads();
    for (int s = 128; s > 0; s >>= 1) {
        if (t < s) {
#pragma unroll
            for (int e = 0; e < EE; e++)
                red[t * RSTR + e] = fmaxf(red[t * RSTR + e], red[(t + s) * RSTR + e]);
        }
        __syncthreads();
    }
    float mg[EE];
#pragma unroll
    for (int e = 0; e < EE; e++) mg[e] = red[e];
    __syncthreads();

    float s_[EE];
#pragma unroll
    for (int e = 0; e < EE; e++) s_[e] = 0.f;
    for (int k = 0; k < NN / 256; k++) {
        const float4* row = (const float4*)(wb + ((long)(k * 256 + t)) * EE);
#pragma unroll
        for (int q = 0; q < 4; q++) {
            float4 v = row[q];
            s_[q * 4 + 0] += __expf(v.x - mg[q * 4 + 0]);
            s_[q * 4 + 1] += __expf(v.y - mg[q * 4 + 1]);
            s_[q * 4 + 2] += __expf(v.z - mg[q * 4 + 2]);
            s_[q * 4 + 3] += __expf(v.w - mg[q * 4 + 3]);
        }
    }
#pragma unroll
    for (int e = 0; e < EE; e++) red[t * RSTR + e] = s_[e];
    __syncthreads();
    for (int s = 128; s > 0; s >>= 1) {
        if (t < s) {
#pragma unroll
            for (int e = 0; e < EE; e++)
                red[t * RSTR + e] += red[(t + s) * RSTR + e];
        }
        __syncthreads();
    }
    if (t < EE) {
        gmax[b * EE + t] = mg[t];
        grcp[b * EE + t] = 1.f / red[t];
    }
}

// K3: xin[b,e,d] += sum_n dispatch[b,n,e] * x[b,n,d]   (atomic over n-chunks)
__global__ __launch_bounds__(192)
void k_xin(const float* __restrict__ z, const float* __restrict__ a,
           const float* __restrict__ w, const float* __restrict__ gmax,
           const float* __restrict__ grcp, float* __restrict__ xin) {
    __shared__ float disp[256 * EE];   // 16 KB
    int b = blockIdx.y, chunk = blockIdx.x, t = threadIdx.x;

    const float* wrow = w + ((long)b * NN + (long)chunk * 256) * EE;
    for (int i = t; i < 256 * EE; i += 192) {
        int e = i & 15;
        disp[i] = __expf(wrow[i] - gmax[b * EE + e]) * grcp[b * EE + e];
    }
    __syncthreads();

    float acc[EE];
#pragma unroll
    for (int e = 0; e < EE; e++) acc[e] = 0.f;

    for (int n = 0; n < 256; n++) {
        int ng = chunk * 256 + n;
        float xv;
        if (t < DZ) xv = z[((long)b * NN + ng) * DZ + t];
        else        xv = a[((long)b * NN + ng) * DA + (t - DZ)];
        const float4* dp = (const float4*)(disp + n * EE);
#pragma unroll
        for (int q = 0; q < 4; q++) {
            float4 p = dp[q];
            acc[q * 4 + 0] += p.x * xv;
            acc[q * 4 + 1] += p.y * xv;
            acc[q * 4 + 2] += p.z * xv;
            acc[q * 4 + 3] += p.w * xv;
        }
    }
#pragma unroll
    for (int e = 0; e < EE; e++)
        atomicAdd(&xin[((long)b * EE + e) * DD + t], acc[e]);
}

// K4: per-expert fused 3-layer MLP on 8 batch-rows per block
__global__ __launch_bounds__(512)
void k_mlp(const float* __restrict__ xin,
           const float* __restrict__ W1, const float* __restrict__ b1,
           const float* __restrict__ g1, const float* __restrict__ be1,
           const float* __restrict__ W2, const float* __restrict__ b2,
           const float* __restrict__ g2, const float* __restrict__ be2,
           const float* __restrict__ W3, const float* __restrict__ b3,
           float* __restrict__ eout) {
    __shared__ float xs[8][DD];
    __shared__ float h1s[8][HH];
    __shared__ float h2s[8][HH];
    __shared__ float redA[8][8], redB[8][8];

    int bg = blockIdx.x, e = blockIdx.y, t = threadIdx.x;
    int wave = t >> 6, lane = t & 63;

    for (int i = t; i < 8 * DD; i += 512) {
        int r = i / DD, d = i % DD;
        xs[r][d] = xin[(((long)(bg * 8 + r)) * EE + e) * DD + d];
    }
    __syncthreads();

    float accv[8];
    // ---- layer 1: D -> H1
    {
        float bj = b1[e * HH + t];
#pragma unroll
        for (int r = 0; r < 8; r++) accv[r] = bj;
        const float* Wp = W1 + (long)e * DD * HH + t;
#pragma unroll 4
        for (int d = 0; d < DD; d++) {
            float wv = Wp[(long)d * HH];
#pragma unroll
            for (int r = 0; r < 8; r++) accv[r] += xs[r][d] * wv;
        }
    }
    // LN + mish -> h1s
    {
        float s[8], q[8];
#pragma unroll
        for (int r = 0; r < 8; r++) { s[r] = accv[r]; q[r] = accv[r] * accv[r]; }
        for (int off = 32; off > 0; off >>= 1) {
#pragma unroll
            for (int r = 0; r < 8; r++) {
                s[r] += __shfl_xor(s[r], off);
                q[r] += __shfl_xor(q[r], off);
            }
        }
        if (lane == 0) {
#pragma unroll
            for (int r = 0; r < 8; r++) { redA[wave][r] = s[r]; redB[wave][r] = q[r]; }
        }
        __syncthreads();
        float gj = g1[e * HH + t], bj = be1[e * HH + t];
#pragma unroll
        for (int r = 0; r < 8; r++) {
            float ss = 0.f, qq = 0.f;
#pragma unroll
            for (int wv = 0; wv < 8; wv++) { ss += redA[wv][r]; qq += redB[wv][r]; }
            float mean = ss / HH;
            float var = qq / HH - mean * mean;
            float rstd = rsqrtf(var + LN_EPS);
            h1s[r][t] = mishf((accv[r] - mean) * rstd * gj + bj);
        }
        __syncthreads();
    }
    // ---- layer 2: H1 -> H2
    {
        float bj = b2[e * HH + t];
#pragma unroll
        for (int r = 0; r < 8; r++) accv[r] = bj;
        const float* Wp = W2 + (long)e * HH * HH + t;
#pragma unroll 4
        for (int k = 0; k < HH; k++) {
            float wv = Wp[(long)k * HH];
#pragma unroll
            for (int r = 0; r < 8; r++) accv[r] += h1s[r][k] * wv;
        }
    }
    __syncthreads();   // protect redA/redB reuse
    {
        float s[8], q[8];
#pragma unroll
        for (int r = 0; r < 8; r++) { s[r] = accv[r]; q[r] = accv[r] * accv[r]; }
        for (int off = 32; off > 0; off >>= 1) {
#pragma unroll
            for (int r = 0; r < 8; r++) {
                s[r] += __shfl_xor(s[r], off);
                q[r] += __shfl_xor(q[r], off);
            }
        }
        if (lane == 0) {
#pragma unroll
            for (int r = 0; r < 8; r++) { redA[wave][r] = s[r]; redB[wave][r] = q[r]; }
        }
        __syncthreads();
        float gj = g2[e * HH + t], bj = be2[e * HH + t];
#pragma unroll
        for (int r = 0; r < 8; r++) {
            float ss = 0.f, qq = 0.f;
#pragma unroll
            for (int wv = 0; wv < 8; wv++) { ss += redA[wv][r]; qq += redB[wv][r]; }
            float mean = ss / HH;
            float var = qq / HH - mean * mean;
            float rstd = rsqrtf(var + LN_EPS);
            h2s[r][t] = mishf((accv[r] - mean) * rstd * gj + bj);
        }
        __syncthreads();
    }
    // ---- layer 3: H2 -> DZ (threads 0..127)
    if (t < DZ) {
        float acc3[8];
        float bj = b3[e * DZ + t];
#pragma unroll
        for (int r = 0; r < 8; r++) acc3[r] = bj;
        const float* Wp = W3 + (long)e * HH * DZ + t;
#pragma unroll 4
        for (int k = 0; k < HH; k++) {
            float wv = Wp[(long)k * DZ];
#pragma unroll
            for (int r = 0; r < 8; r++) acc3[r] += h2s[r][k] * wv;
        }
#pragma unroll
        for (int r = 0; r < 8; r++)
            eout[(((long)(bg * 8 + r)) * EE + e) * DZ + t] = acc3[r];
    }
}

// K5: combine softmax over E (per token) and mix expert outputs
__global__ __launch_bounds__(256)
void k_combine(const float* __restrict__ w, const float* __restrict__ eout,
               float* __restrict__ out) {
    __shared__ float comb[64][EE];
    __shared__ float eo[EE * DZ];   // 8 KB
    int b = blockIdx.y, n0 = blockIdx.x * 64, t = threadIdx.x;

    for (int i = t; i < EE * DZ; i += 256) eo[i] = eout[(long)b * EE * DZ + i];

    int tok = t >> 2, sub = t & 3;
    const float4 wv = *(const float4*)(w + ((long)b * NN + n0 + tok) * EE + sub * 4);
    float mx = fmaxf(fmaxf(wv.x, wv.y), fmaxf(wv.z, wv.w));
    mx = fmaxf(mx, __shfl_xor(mx, 1, 4));
    mx = fmaxf(mx, __shfl_xor(mx, 2, 4));
    float e0 = __expf(wv.x - mx), e1 = __expf(wv.y - mx);
    float e2 = __expf(wv.z - mx), e3 = __expf(wv.w - mx);
    float s = e0 + e1 + e2 + e3;
    s += __shfl_xor(s, 1, 4);
    s += __shfl_xor(s, 2, 4);
    float rs = 1.f / s;
    comb[tok][sub * 4 + 0] = e0 * rs;
    comb[tok][sub * 4 + 1] = e1 * rs;
    comb[tok][sub * 4 + 2] = e2 * rs;
    comb[tok][sub * 4 + 3] = e3 * rs;
    __syncthreads();

    for (int i = t; i < 64 * DZ; i += 256) {
        int tk = i >> 7, c = i & 127;
        float acc = 0.f;
#pragma unroll
        for (int e = 0; e < EE; e++) acc += comb[tk][e] * eo[e * DZ + c];
        out[((long)b * NN + n0 + tk) * DZ + c] = acc;
    }
}

extern "C" void kernel_launch(void* const* d_in, const int* in_sizes, int n_in,
                              void* d_out, int out_size, void* d_ws, size_t ws_size,
                              hipStream_t stream) {
    const float* z   = (const float*)d_in[0];
    const float* a   = (const float*)d_in[1];
    const float* phi = (const float*)d_in[2];
    const float* W1  = (const float*)d_in[3];
    const float* b1  = (const float*)d_in[4];
    const float* g1  = (const float*)d_in[5];
    const float* be1 = (const float*)d_in[6];
    const float* W2  = (const float*)d_in[7];
    const float* b2  = (const float*)d_in[8];
    const float* g2  = (const float*)d_in[9];
    const float* be2 = (const float*)d_in[10];
    const float* W3  = (const float*)d_in[11];
    const float* b3  = (const float*)d_in[12];
    float* out = (float*)d_out;

    char* p = (char*)d_ws;
    float* w    = (float*)p; p += (size_t)BB * NN * EE * 4;   // 8.39 MB
    float* gmax = (float*)p; p += (size_t)BB * EE * 4;
    float* grcp = (float*)p; p += (size_t)BB * EE * 4;
    float* xin  = (float*)p; p += (size_t)BB * EE * DD * 4;   // 786 KB
    float* eout = (float*)p; p += (size_t)BB * EE * DZ * 4;   // 524 KB

    hipMemsetAsync(xin, 0, (size_t)BB * EE * DD * 4, stream);

    k_weights<<<BB * NN / 256, 256, 0, stream>>>(z, a, phi, w);
    k_stats<<<BB, 256, 0, stream>>>(w, gmax, grcp);
    k_xin<<<dim3(NN / 256, BB), 192, 0, stream>>>(z, a, w, gmax, grcp, xin);
    k_mlp<<<dim3(8, EE), 512, 0, stream>>>(xin, W1, b1, g1, be1,
                                           W2, b2, g2, be2, W3, b3, eout);
    k_combine<<<dim3(NN / 64, BB), 256, 0, stream>>>(w, eout, out);
}

// Round 2
// 194.847 us; speedup vs baseline: 1.1254x; 1.1254x over previous
//
#include <hip/hip_runtime.h>
#include <math.h>

#define BB 64
#define NN 2048
#define DZ 128
#define DA 64
#define DD 192
#define EE 16
#define HH 512
#define LN_EPS 1e-5f

__device__ __forceinline__ float mishf(float x) {
    float sp = (x > 20.f) ? x : log1pf(__expf(x));
    return x * tanhf(sp);
}

// K1: weights[b,n,e] = sum_d x[b,n,d] * phi[d,e]
__global__ __launch_bounds__(256)
void k_weights(const float* __restrict__ z, const float* __restrict__ a,
               const float* __restrict__ phi, float* __restrict__ w) {
    __shared__ float phis[DD * EE];
    int t = threadIdx.x;
    for (int i = t; i < DD * EE; i += 256) phis[i] = phi[i];
    __syncthreads();

    long token = (long)blockIdx.x * 256 + t;   // 0 .. B*N-1
    int b = (int)(token >> 11);
    int n = (int)(token & (NN - 1));

    const float4* zr = (const float4*)(z + ((long)b * NN + n) * DZ);
    const float4* ar = (const float4*)(a + ((long)b * NN + n) * DA);

    float acc[EE];
#pragma unroll
    for (int e = 0; e < EE; e++) acc[e] = 0.f;

#pragma unroll 4
    for (int q = 0; q < DZ / 4; q++) {
        float4 v = zr[q];
        const float* pv = &v.x;
#pragma unroll
        for (int c = 0; c < 4; c++) {
            float xv = pv[c];
            const float4* pr = (const float4*)(phis + (q * 4 + c) * EE);
#pragma unroll
            for (int e4 = 0; e4 < 4; e4++) {
                float4 p = pr[e4];
                acc[e4 * 4 + 0] += xv * p.x;
                acc[e4 * 4 + 1] += xv * p.y;
                acc[e4 * 4 + 2] += xv * p.z;
                acc[e4 * 4 + 3] += xv * p.w;
            }
        }
    }
#pragma unroll 4
    for (int q = 0; q < DA / 4; q++) {
        float4 v = ar[q];
        const float* pv = &v.x;
#pragma unroll
        for (int c = 0; c < 4; c++) {
            float xv = pv[c];
            const float4* pr = (const float4*)(phis + (DZ + q * 4 + c) * EE);
#pragma unroll
            for (int e4 = 0; e4 < 4; e4++) {
                float4 p = pr[e4];
                acc[e4 * 4 + 0] += xv * p.x;
                acc[e4 * 4 + 1] += xv * p.y;
                acc[e4 * 4 + 2] += xv * p.z;
                acc[e4 * 4 + 3] += xv * p.w;
            }
        }
    }

    float4* wout = (float4*)(w + token * EE);
#pragma unroll
    for (int e4 = 0; e4 < 4; e4++)
        wout[e4] = make_float4(acc[e4 * 4 + 0], acc[e4 * 4 + 1],
                               acc[e4 * 4 + 2], acc[e4 * 4 + 3]);
}

// K2: per (b,e): max over n and 1/sum(exp(w-max)) over n
#define RSTR 17
__global__ __launch_bounds__(256)
void k_stats(const float* __restrict__ w, float* __restrict__ gmax,
             float* __restrict__ grcp) {
    __shared__ float red[256 * RSTR];
    int b = blockIdx.x, t = threadIdx.x;
    const float* wb = w + (long)b * NN * EE;

    float m[EE];
#pragma unroll
    for (int e = 0; e < EE; e++) m[e] = -1e30f;
    for (int k = 0; k < NN / 256; k++) {
        const float4* row = (const float4*)(wb + ((long)(k * 256 + t)) * EE);
#pragma unroll
        for (int q = 0; q < 4; q++) {
            float4 v = row[q];
            m[q * 4 + 0] = fmaxf(m[q * 4 + 0], v.x);
            m[q * 4 + 1] = fmaxf(m[q * 4 + 1], v.y);
            m[q * 4 + 2] = fmaxf(m[q * 4 + 2], v.z);
            m[q * 4 + 3] = fmaxf(m[q * 4 + 3], v.w);
        }
    }
#pragma unroll
    for (int e = 0; e < EE; e++) red[t * RSTR + e] = m[e];
    __syncthreads();
    for (int s = 128; s > 0; s >>= 1) {
        if (t < s) {
#pragma unroll
            for (int e = 0; e < EE; e++)
                red[t * RSTR + e] = fmaxf(red[t * RSTR + e], red[(t + s) * RSTR + e]);
        }
        __syncthreads();
    }
    float mg[EE];
#pragma unroll
    for (int e = 0; e < EE; e++) mg[e] = red[e];
    __syncthreads();

    float s_[EE];
#pragma unroll
    for (int e = 0; e < EE; e++) s_[e] = 0.f;
    for (int k = 0; k < NN / 256; k++) {
        const float4* row = (const float4*)(wb + ((long)(k * 256 + t)) * EE);
#pragma unroll
        for (int q = 0; q < 4; q++) {
            float4 v = row[q];
            s_[q * 4 + 0] += __expf(v.x - mg[q * 4 + 0]);
            s_[q * 4 + 1] += __expf(v.y - mg[q * 4 + 1]);
            s_[q * 4 + 2] += __expf(v.z - mg[q * 4 + 2]);
            s_[q * 4 + 3] += __expf(v.w - mg[q * 4 + 3]);
        }
    }
#pragma unroll
    for (int e = 0; e < EE; e++) red[t * RSTR + e] = s_[e];
    __syncthreads();
    for (int s = 128; s > 0; s >>= 1) {
        if (t < s) {
#pragma unroll
            for (int e = 0; e < EE; e++)
                red[t * RSTR + e] += red[(t + s) * RSTR + e];
        }
        __syncthreads();
    }
    if (t < EE) {
        gmax[b * EE + t] = mg[t];
        grcp[b * EE + t] = 1.f / red[t];
    }
}

// K3: xin[e,b,d] += sum_n dispatch[b,n,e] * x[b,n,d]   (atomic over n-chunks)
__global__ __launch_bounds__(192)
void k_xin(const float* __restrict__ z, const float* __restrict__ a,
           const float* __restrict__ w, const float* __restrict__ gmax,
           const float* __restrict__ grcp, float* __restrict__ xin) {
    __shared__ float disp[256 * EE];   // 16 KB
    int b = blockIdx.y, chunk = blockIdx.x, t = threadIdx.x;

    const float* wrow = w + ((long)b * NN + (long)chunk * 256) * EE;
    for (int i = t; i < 256 * EE; i += 192) {
        int e = i & 15;
        disp[i] = __expf(wrow[i] - gmax[b * EE + e]) * grcp[b * EE + e];
    }
    __syncthreads();

    float acc[EE];
#pragma unroll
    for (int e = 0; e < EE; e++) acc[e] = 0.f;

    for (int n = 0; n < 256; n++) {
        int ng = chunk * 256 + n;
        float xv;
        if (t < DZ) xv = z[((long)b * NN + ng) * DZ + t];
        else        xv = a[((long)b * NN + ng) * DA + (t - DZ)];
        const float4* dp = (const float4*)(disp + n * EE);
#pragma unroll
        for (int q = 0; q < 4; q++) {
            float4 p = dp[q];
            acc[q * 4 + 0] += p.x * xv;
            acc[q * 4 + 1] += p.y * xv;
            acc[q * 4 + 2] += p.z * xv;
            acc[q * 4 + 3] += p.w * xv;
        }
    }
    // xin layout: [e][b][d]  (expert-major, rows contiguous for the GEMMs)
#pragma unroll
    for (int e = 0; e < EE; e++)
        atomicAdd(&xin[((long)e * BB + b) * DD + t], acc[e]);
}

// Generic per-expert GEMM: Y[e-rows][OUT] = act(X) @ W_e + bias_e
// act = identity (gemm1) or LN+mish using stats_in (gemm2/3).
// Optionally accumulates per-row (sum, sumsq) of the output into stats_out.
// Block: 256 thr, 8 rows x CT cols, full K. wave->2 rows, lane->CPT cols.
template<int K, int OUT, int CT, bool LN_IN, bool STATS_OUT, bool SCATTER>
__global__ __launch_bounds__(256)
void k_gemm(const float* __restrict__ X, const float* __restrict__ stats_in,
            const float* __restrict__ g, const float* __restrict__ be,
            const float* __restrict__ W, const float* __restrict__ bias,
            float* __restrict__ Y, float* __restrict__ stats_out) {
    constexpr int CPT = CT / 64;
    __shared__ float xs[8][K];
    __shared__ float mrs[8][2];

    int cb = blockIdx.x, rb = blockIdx.y, e = blockIdx.z;
    int t = threadIdx.x;
    int b0 = rb * 8;
    long rowbase = (long)e * BB + b0;

    if constexpr (LN_IN) {
        if (t < 8) {
            float s = stats_in[(rowbase + t) * 2 + 0];
            float q = stats_in[(rowbase + t) * 2 + 1];
            float mean = s * (1.f / K);
            float var = q * (1.f / K) - mean * mean;
            mrs[t][0] = mean;
            mrs[t][1] = rsqrtf(var + LN_EPS);
        }
        __syncthreads();
        for (int i = t; i < 8 * K / 4; i += 256) {
            int r = i / (K / 4), k4 = i % (K / 4);
            float4 v  = *(const float4*)(X + (rowbase + r) * K + k4 * 4);
            float4 gg = *(const float4*)(g + (long)e * K + k4 * 4);
            float4 bb = *(const float4*)(be + (long)e * K + k4 * 4);
            float mean = mrs[r][0], rstd = mrs[r][1];
            v.x = mishf((v.x - mean) * rstd * gg.x + bb.x);
            v.y = mishf((v.y - mean) * rstd * gg.y + bb.y);
            v.z = mishf((v.z - mean) * rstd * gg.z + bb.z);
            v.w = mishf((v.w - mean) * rstd * gg.w + bb.w);
            *(float4*)&xs[r][k4 * 4] = v;
        }
    } else {
        for (int i = t; i < 8 * K / 4; i += 256) {
            int r = i / (K / 4), k4 = i % (K / 4);
            *(float4*)&xs[r][k4 * 4] =
                *(const float4*)(X + (rowbase + r) * K + k4 * 4);
        }
    }
    __syncthreads();

    int wave = t >> 6, lane = t & 63;
    int r0 = wave * 2;
    int c0 = cb * CT + lane * CPT;

    const float* Wp = W + (long)e * K * OUT + c0;
    float acc0[CPT], acc1[CPT];
#pragma unroll
    for (int j = 0; j < CPT; j++) {
        float bv = bias[(long)e * OUT + c0 + j];
        acc0[j] = bv;
        acc1[j] = bv;
    }

#pragma unroll 8
    for (int k = 0; k < K; k++) {
        float wv[CPT];
        if constexpr (CPT == 4) *(float4*)wv = *(const float4*)Wp;
        else                    *(float2*)wv = *(const float2*)Wp;
        float x0 = xs[r0][k], x1 = xs[r0 + 1][k];
#pragma unroll
        for (int j = 0; j < CPT; j++) {
            acc0[j] += x0 * wv[j];
            acc1[j] += x1 * wv[j];
        }
        Wp += OUT;
    }

    // write output
    if constexpr (!SCATTER) {
        float* y0 = Y + (rowbase + r0) * OUT + c0;
        float* y1 = Y + (rowbase + r0 + 1) * OUT + c0;
        if constexpr (CPT == 4) {
            *(float4*)y0 = *(float4*)acc0;
            *(float4*)y1 = *(float4*)acc1;
        } else {
            *(float2*)y0 = *(float2*)acc0;
            *(float2*)y1 = *(float2*)acc1;
        }
    } else {
        // eout layout [b][e][OUT]
        float* y0 = Y + ((long)(b0 + r0) * EE + e) * OUT + c0;
        float* y1 = Y + ((long)(b0 + r0 + 1) * EE + e) * OUT + c0;
        if constexpr (CPT == 4) {
            *(float4*)y0 = *(float4*)acc0;
            *(float4*)y1 = *(float4*)acc1;
        } else {
            *(float2*)y0 = *(float2*)acc0;
            *(float2*)y1 = *(float2*)acc1;
        }
    }

    if constexpr (STATS_OUT) {
        float s0 = 0.f, q0 = 0.f, s1 = 0.f, q1 = 0.f;
#pragma unroll
        for (int j = 0; j < CPT; j++) {
            s0 += acc0[j]; q0 += acc0[j] * acc0[j];
            s1 += acc1[j]; q1 += acc1[j] * acc1[j];
        }
        for (int off = 32; off > 0; off >>= 1) {
            s0 += __shfl_xor(s0, off);
            q0 += __shfl_xor(q0, off);
            s1 += __shfl_xor(s1, off);
            q1 += __shfl_xor(q1, off);
        }
        if (lane == 0) {
            atomicAdd(&stats_out[(rowbase + r0) * 2 + 0], s0);
            atomicAdd(&stats_out[(rowbase + r0) * 2 + 1], q0);
            atomicAdd(&stats_out[(rowbase + r0 + 1) * 2 + 0], s1);
            atomicAdd(&stats_out[(rowbase + r0 + 1) * 2 + 1], q1);
        }
    }
}

// K5: combine softmax over E (per token) and mix expert outputs
__global__ __launch_bounds__(256)
void k_combine(const float* __restrict__ w, const float* __restrict__ eout,
               float* __restrict__ out) {
    __shared__ float comb[64][EE];
    __shared__ float eo[EE * DZ];   // 8 KB
    int b = blockIdx.y, n0 = blockIdx.x * 64, t = threadIdx.x;

    for (int i = t; i < EE * DZ; i += 256) eo[i] = eout[(long)b * EE * DZ + i];

    int tok = t >> 2, sub = t & 3;
    const float4 wv = *(const float4*)(w + ((long)b * NN + n0 + tok) * EE + sub * 4);
    float mx = fmaxf(fmaxf(wv.x, wv.y), fmaxf(wv.z, wv.w));
    mx = fmaxf(mx, __shfl_xor(mx, 1, 4));
    mx = fmaxf(mx, __shfl_xor(mx, 2, 4));
    float e0 = __expf(wv.x - mx), e1 = __expf(wv.y - mx);
    float e2 = __expf(wv.z - mx), e3 = __expf(wv.w - mx);
    float s = e0 + e1 + e2 + e3;
    s += __shfl_xor(s, 1, 4);
    s += __shfl_xor(s, 2, 4);
    float rs = 1.f / s;
    comb[tok][sub * 4 + 0] = e0 * rs;
    comb[tok][sub * 4 + 1] = e1 * rs;
    comb[tok][sub * 4 + 2] = e2 * rs;
    comb[tok][sub * 4 + 3] = e3 * rs;
    __syncthreads();

    for (int i = t; i < 64 * DZ; i += 256) {
        int tk = i >> 7, c = i & 127;
        float acc = 0.f;
#pragma unroll
        for (int e = 0; e < EE; e++) acc += comb[tk][e] * eo[e * DZ + c];
        out[((long)b * NN + n0 + tk) * DZ + c] = acc;
    }
}

extern "C" void kernel_launch(void* const* d_in, const int* in_sizes, int n_in,
                              void* d_out, int out_size, void* d_ws, size_t ws_size,
                              hipStream_t stream) {
    const float* z   = (const float*)d_in[0];
    const float* a   = (const float*)d_in[1];
    const float* phi = (const float*)d_in[2];
    const float* W1  = (const float*)d_in[3];
    const float* b1  = (const float*)d_in[4];
    const float* g1  = (const float*)d_in[5];
    const float* be1 = (const float*)d_in[6];
    const float* W2  = (const float*)d_in[7];
    const float* b2  = (const float*)d_in[8];
    const float* g2  = (const float*)d_in[9];
    const float* be2 = (const float*)d_in[10];
    const float* W3  = (const float*)d_in[11];
    const float* b3  = (const float*)d_in[12];
    float* out = (float*)d_out;

    char* p = (char*)d_ws;
    float* w      = (float*)p; p += (size_t)BB * NN * EE * 4;     // 8.39 MB
    float* gmax   = (float*)p; p += (size_t)BB * EE * 4;
    float* grcp   = (float*)p; p += (size_t)BB * EE * 4;
    float* xin    = (float*)p; p += (size_t)BB * EE * DD * 4;     // 786 KB
    float* eout   = (float*)p; p += (size_t)BB * EE * DZ * 4;     // 524 KB
    float* h1     = (float*)p; p += (size_t)BB * EE * HH * 4;     // 2 MB
    float* h2     = (float*)p; p += (size_t)BB * EE * HH * 4;     // 2 MB
    float* stats1 = (float*)p; p += (size_t)BB * EE * 2 * 4;      // 8 KB
    float* stats2 = (float*)p; p += (size_t)BB * EE * 2 * 4;      // 8 KB

    hipMemsetAsync(xin, 0, (size_t)BB * EE * DD * 4, stream);
    hipMemsetAsync(stats1, 0, (size_t)BB * EE * 2 * 4 * 2, stream);  // stats1+stats2

    k_weights<<<BB * NN / 256, 256, 0, stream>>>(z, a, phi, w);
    k_stats<<<BB, 256, 0, stream>>>(w, gmax, grcp);
    k_xin<<<dim3(NN / 256, BB), 192, 0, stream>>>(z, a, w, gmax, grcp, xin);

    k_gemm<DD, HH, 256, false, true, false>
        <<<dim3(HH / 256, BB / 8, EE), 256, 0, stream>>>(
            xin, nullptr, nullptr, nullptr, W1, b1, h1, stats1);
    k_gemm<HH, HH, 256, true, true, false>
        <<<dim3(HH / 256, BB / 8, EE), 256, 0, stream>>>(
            h1, stats1, g1, be1, W2, b2, h2, stats2);
    k_gemm<HH, DZ, 128, true, false, true>
        <<<dim3(1, BB / 8, EE), 256, 0, stream>>>(
            h2, stats2, g2, be2, W3, b3, eout, nullptr);

    k_combine<<<dim3(NN / 64, BB), 256, 0, stream>>>(w, eout, out);
}

// Round 3
// 159.842 us; speedup vs baseline: 1.3719x; 1.2190x over previous
//
#include <hip/hip_runtime.h>
#include <math.h>

#define BB 64
#define NN 2048
#define DZ 128
#define DA 64
#define DD 192
#define EE 16
#define HH 512
#define LN_EPS 1e-5f

__device__ __forceinline__ float mishf(float x) {
    float sp = (x > 20.f) ? x : log1pf(__expf(x));
    return x * tanhf(sp);
}

// K1: weights[b,n,e] = sum_d x[b,n,d] * phi[d,e]
__global__ __launch_bounds__(256)
void k_weights(const float* __restrict__ z, const float* __restrict__ a,
               const float* __restrict__ phi, float* __restrict__ w) {
    __shared__ float phis[DD * EE];
    int t = threadIdx.x;
    for (int i = t; i < DD * EE; i += 256) phis[i] = phi[i];
    __syncthreads();

    long token = (long)blockIdx.x * 256 + t;   // 0 .. B*N-1
    int b = (int)(token >> 11);
    int n = (int)(token & (NN - 1));

    const float4* zr = (const float4*)(z + ((long)b * NN + n) * DZ);
    const float4* ar = (const float4*)(a + ((long)b * NN + n) * DA);

    float acc[EE];
#pragma unroll
    for (int e = 0; e < EE; e++) acc[e] = 0.f;

#pragma unroll 4
    for (int q = 0; q < DZ / 4; q++) {
        float4 v = zr[q];
        const float* pv = &v.x;
#pragma unroll
        for (int c = 0; c < 4; c++) {
            float xv = pv[c];
            const float4* pr = (const float4*)(phis + (q * 4 + c) * EE);
#pragma unroll
            for (int e4 = 0; e4 < 4; e4++) {
                float4 p = pr[e4];
                acc[e4 * 4 + 0] += xv * p.x;
                acc[e4 * 4 + 1] += xv * p.y;
                acc[e4 * 4 + 2] += xv * p.z;
                acc[e4 * 4 + 3] += xv * p.w;
            }
        }
    }
#pragma unroll 4
    for (int q = 0; q < DA / 4; q++) {
        float4 v = ar[q];
        const float* pv = &v.x;
#pragma unroll
        for (int c = 0; c < 4; c++) {
            float xv = pv[c];
            const float4* pr = (const float4*)(phis + (DZ + q * 4 + c) * EE);
#pragma unroll
            for (int e4 = 0; e4 < 4; e4++) {
                float4 p = pr[e4];
                acc[e4 * 4 + 0] += xv * p.x;
                acc[e4 * 4 + 1] += xv * p.y;
                acc[e4 * 4 + 2] += xv * p.z;
                acc[e4 * 4 + 3] += xv * p.w;
            }
        }
    }

    float4* wout = (float4*)(w + token * EE);
#pragma unroll
    for (int e4 = 0; e4 < 4; e4++)
        wout[e4] = make_float4(acc[e4 * 4 + 0], acc[e4 * 4 + 1],
                               acc[e4 * 4 + 2], acc[e4 * 4 + 3]);
}

// K2: per (b,e): max over n and 1/sum(exp(w-max)) over n
#define RSTR 17
__global__ __launch_bounds__(256)
void k_stats(const float* __restrict__ w, float* __restrict__ gmax,
             float* __restrict__ grcp) {
    __shared__ float red[256 * RSTR];
    int b = blockIdx.x, t = threadIdx.x;
    const float* wb = w + (long)b * NN * EE;

    float m[EE];
#pragma unroll
    for (int e = 0; e < EE; e++) m[e] = -1e30f;
    for (int k = 0; k < NN / 256; k++) {
        const float4* row = (const float4*)(wb + ((long)(k * 256 + t)) * EE);
#pragma unroll
        for (int q = 0; q < 4; q++) {
            float4 v = row[q];
            m[q * 4 + 0] = fmaxf(m[q * 4 + 0], v.x);
            m[q * 4 + 1] = fmaxf(m[q * 4 + 1], v.y);
            m[q * 4 + 2] = fmaxf(m[q * 4 + 2], v.z);
            m[q * 4 + 3] = fmaxf(m[q * 4 + 3], v.w);
        }
    }
#pragma unroll
    for (int e = 0; e < EE; e++) red[t * RSTR + e] = m[e];
    __syncthreads();
    for (int s = 128; s > 0; s >>= 1) {
        if (t < s) {
#pragma unroll
            for (int e = 0; e < EE; e++)
                red[t * RSTR + e] = fmaxf(red[t * RSTR + e], red[(t + s) * RSTR + e]);
        }
        __syncthreads();
    }
    float mg[EE];
#pragma unroll
    for (int e = 0; e < EE; e++) mg[e] = red[e];
    __syncthreads();

    float s_[EE];
#pragma unroll
    for (int e = 0; e < EE; e++) s_[e] = 0.f;
    for (int k = 0; k < NN / 256; k++) {
        const float4* row = (const float4*)(wb + ((long)(k * 256 + t)) * EE);
#pragma unroll
        for (int q = 0; q < 4; q++) {
            float4 v = row[q];
            s_[q * 4 + 0] += __expf(v.x - mg[q * 4 + 0]);
            s_[q * 4 + 1] += __expf(v.y - mg[q * 4 + 1]);
            s_[q * 4 + 2] += __expf(v.z - mg[q * 4 + 2]);
            s_[q * 4 + 3] += __expf(v.w - mg[q * 4 + 3]);
        }
    }
#pragma unroll
    for (int e = 0; e < EE; e++) red[t * RSTR + e] = s_[e];
    __syncthreads();
    for (int s = 128; s > 0; s >>= 1) {
        if (t < s) {
#pragma unroll
            for (int e = 0; e < EE; e++)
                red[t * RSTR + e] += red[(t + s) * RSTR + e];
        }
        __syncthreads();
    }
    if (t < EE) {
        gmax[b * EE + t] = mg[t];
        grcp[b * EE + t] = 1.f / red[t];
    }
}

// K3: xin[e,b,d] += sum_n dispatch[b,n,e] * x[b,n,d]   (atomic over n-chunks)
__global__ __launch_bounds__(192)
void k_xin(const float* __restrict__ z, const float* __restrict__ a,
           const float* __restrict__ w, const float* __restrict__ gmax,
           const float* __restrict__ grcp, float* __restrict__ xin) {
    __shared__ float disp[256 * EE];   // 16 KB
    int b = blockIdx.y, chunk = blockIdx.x, t = threadIdx.x;

    const float* wrow = w + ((long)b * NN + (long)chunk * 256) * EE;
    for (int i = t; i < 256 * EE; i += 192) {
        int e = i & 15;
        disp[i] = __expf(wrow[i] - gmax[b * EE + e]) * grcp[b * EE + e];
    }
    __syncthreads();

    float acc[EE];
#pragma unroll
    for (int e = 0; e < EE; e++) acc[e] = 0.f;

    for (int n = 0; n < 256; n++) {
        int ng = chunk * 256 + n;
        float xv;
        if (t < DZ) xv = z[((long)b * NN + ng) * DZ + t];
        else        xv = a[((long)b * NN + ng) * DA + (t - DZ)];
        const float4* dp = (const float4*)(disp + n * EE);
#pragma unroll
        for (int q = 0; q < 4; q++) {
            float4 p = dp[q];
            acc[q * 4 + 0] += p.x * xv;
            acc[q * 4 + 1] += p.y * xv;
            acc[q * 4 + 2] += p.z * xv;
            acc[q * 4 + 3] += p.w * xv;
        }
    }
    // xin layout: [e][b][d]  (expert-major, rows contiguous for the GEMMs)
#pragma unroll
    for (int e = 0; e < EE; e++)
        atomicAdd(&xin[((long)e * BB + b) * DD + t], acc[e]);
}

// Split-K per-expert GEMM partial: Yp[ks][e*64+r][OUT] = X[e-rows][k-slice] @ W_e
// Block: 256 thr = 64 rows x 32 cols; thread = 2 rows x 4 cols; k vectorized x4.
// grid: (OUT/32, KS, EE)
template<int K, int OUT, int KSLICE, bool ADD_BIAS>
__global__ __launch_bounds__(256)
void k_gemm(const float* __restrict__ X, const float* __restrict__ W,
            const float* __restrict__ bias, float* __restrict__ Yp) {
    constexpr int SP = KSLICE + 4;       // stride %32 == 4 -> 2-way LDS alias (free), 16B aligned
    constexpr int K4 = KSLICE / 4;
    __shared__ float xs[64 * SP];

    int cb = blockIdx.x, ks = blockIdx.y, e = blockIdx.z;
    int t = threadIdx.x;
    int k0 = ks * KSLICE;

    // stage x slice: 64 rows x KSLICE, coalesced float4
    for (int i = t; i < 64 * K4; i += 256) {
        int r = i / K4, k4 = i % K4;
        *(float4*)&xs[r * SP + k4 * 4] =
            *(const float4*)(X + ((long)e * BB + r) * K + k0 + k4 * 4);
    }
    __syncthreads();

    int c = cb * 32 + (t & 7) * 4;
    int r0 = (t >> 3) * 2;
    const float* Wp = W + ((long)e * K + k0) * OUT + c;

    float acc0[4], acc1[4];
#pragma unroll
    for (int j = 0; j < 4; j++) {
        float bv = ADD_BIAS ? bias[(long)e * OUT + c + j] : 0.f;
        acc0[j] = bv;
        acc1[j] = bv;
    }

#pragma unroll 4
    for (int k4 = 0; k4 < K4; k4++) {
        float4 x0 = *(const float4*)&xs[r0 * SP + k4 * 4];
        float4 x1 = *(const float4*)&xs[(r0 + 1) * SP + k4 * 4];
        const float* xp0 = &x0.x;
        const float* xp1 = &x1.x;
#pragma unroll
        for (int j = 0; j < 4; j++) {
            float4 wv = *(const float4*)(Wp + (long)(k4 * 4 + j) * OUT);
            float xa = xp0[j], xb = xp1[j];
            acc0[0] += xa * wv.x; acc0[1] += xa * wv.y;
            acc0[2] += xa * wv.z; acc0[3] += xa * wv.w;
            acc1[0] += xb * wv.x; acc1[1] += xb * wv.y;
            acc1[2] += xb * wv.z; acc1[3] += xb * wv.w;
        }
    }

    float* yp = Yp + ((long)ks * (EE * BB) + (long)e * BB + r0) * OUT + c;
    *(float4*)yp         = make_float4(acc0[0], acc0[1], acc0[2], acc0[3]);
    *(float4*)(yp + OUT) = make_float4(acc1[0], acc1[1], acc1[2], acc1[3]);
}

// Reduce KS partials + bias, then LayerNorm + mish.  One block per row, OUT=512.
template<int KS, bool HAS_BIAS>
__global__ __launch_bounds__(256)
void k_lnact(const float* __restrict__ Yp, const float* __restrict__ bias,
             const float* __restrict__ g, const float* __restrict__ be,
             float* __restrict__ Yo) {
    __shared__ float redS[4], redQ[4];
    int row = blockIdx.x, t = threadIdx.x;
    int e = row >> 6;

    float v[2];
#pragma unroll
    for (int j = 0; j < 2; j++) {
        int cj = t + j * 256;
        float s = HAS_BIAS ? bias[(long)e * HH + cj] : 0.f;
#pragma unroll
        for (int ks = 0; ks < KS; ks++)
            s += Yp[((long)ks * (EE * BB) + row) * HH + cj];
        v[j] = s;
    }
    float s = v[0] + v[1];
    float q = v[0] * v[0] + v[1] * v[1];
    for (int off = 32; off > 0; off >>= 1) {
        s += __shfl_xor(s, off);
        q += __shfl_xor(q, off);
    }
    int wave = t >> 6, lane = t & 63;
    if (lane == 0) { redS[wave] = s; redQ[wave] = q; }
    __syncthreads();
    float S = redS[0] + redS[1] + redS[2] + redS[3];
    float Q = redQ[0] + redQ[1] + redQ[2] + redQ[3];
    float mean = S * (1.f / HH);
    float var = Q * (1.f / HH) - mean * mean;
    float rstd = rsqrtf(var + LN_EPS);

#pragma unroll
    for (int j = 0; j < 2; j++) {
        int cj = t + j * 256;
        float gg = g[(long)e * HH + cj], bb = be[(long)e * HH + cj];
        Yo[(long)row * HH + cj] = mishf((v[j] - mean) * rstd * gg + bb);
    }
}

// Reduce gemm3 partials + bias, scatter to eout[b][e][DZ]. 2 rows per block.
template<int KS>
__global__ __launch_bounds__(256)
void k_fin3(const float* __restrict__ p3, const float* __restrict__ b3,
            float* __restrict__ eout) {
    int t = threadIdx.x;
    int row = blockIdx.x * 2 + (t >> 7);   // 0..1023  (= e*64+b)
    int c = t & 127;
    int e = row >> 6, b = row & 63;
    float s = b3[(long)e * DZ + c];
#pragma unroll
    for (int ks = 0; ks < KS; ks++)
        s += p3[((long)ks * (EE * BB) + row) * DZ + c];
    eout[((long)b * EE + e) * DZ + c] = s;
}

// K5: combine softmax over E (per token) and mix expert outputs
__global__ __launch_bounds__(256)
void k_combine(const float* __restrict__ w, const float* __restrict__ eout,
               float* __restrict__ out) {
    __shared__ float comb[64][EE];
    __shared__ float eo[EE * DZ];   // 8 KB
    int b = blockIdx.y, n0 = blockIdx.x * 64, t = threadIdx.x;

    for (int i = t; i < EE * DZ; i += 256) eo[i] = eout[(long)b * EE * DZ + i];

    int tok = t >> 2, sub = t & 3;
    const float4 wv = *(const float4*)(w + ((long)b * NN + n0 + tok) * EE + sub * 4);
    float mx = fmaxf(fmaxf(wv.x, wv.y), fmaxf(wv.z, wv.w));
    mx = fmaxf(mx, __shfl_xor(mx, 1, 4));
    mx = fmaxf(mx, __shfl_xor(mx, 2, 4));
    float e0 = __expf(wv.x - mx), e1 = __expf(wv.y - mx);
    float e2 = __expf(wv.z - mx), e3 = __expf(wv.w - mx);
    float s = e0 + e1 + e2 + e3;
    s += __shfl_xor(s, 1, 4);
    s += __shfl_xor(s, 2, 4);
    float rs = 1.f / s;
    comb[tok][sub * 4 + 0] = e0 * rs;
    comb[tok][sub * 4 + 1] = e1 * rs;
    comb[tok][sub * 4 + 2] = e2 * rs;
    comb[tok][sub * 4 + 3] = e3 * rs;
    __syncthreads();

    for (int i = t; i < 64 * DZ; i += 256) {
        int tk = i >> 7, c = i & 127;
        float acc = 0.f;
#pragma unroll
        for (int e = 0; e < EE; e++) acc += comb[tk][e] * eo[e * DZ + c];
        out[((long)b * NN + n0 + tk) * DZ + c] = acc;
    }
}

extern "C" void kernel_launch(void* const* d_in, const int* in_sizes, int n_in,
                              void* d_out, int out_size, void* d_ws, size_t ws_size,
                              hipStream_t stream) {
    const float* z   = (const float*)d_in[0];
    const float* a   = (const float*)d_in[1];
    const float* phi = (const float*)d_in[2];
    const float* W1  = (const float*)d_in[3];
    const float* b1  = (const float*)d_in[4];
    const float* g1  = (const float*)d_in[5];
    const float* be1 = (const float*)d_in[6];
    const float* W2  = (const float*)d_in[7];
    const float* b2  = (const float*)d_in[8];
    const float* g2  = (const float*)d_in[9];
    const float* be2 = (const float*)d_in[10];
    const float* W3  = (const float*)d_in[11];
    const float* b3  = (const float*)d_in[12];
    float* out = (float*)d_out;

    char* p = (char*)d_ws;
    float* w    = (float*)p; p += (size_t)BB * NN * EE * 4;          // 8.39 MB
    float* gmax = (float*)p; p += (size_t)BB * EE * 4;
    float* grcp = (float*)p; p += (size_t)BB * EE * 4;
    float* xin  = (float*)p; p += (size_t)BB * EE * DD * 4;          // 786 KB
    // time-shared partial scratch (max user = h2p: 4 * 1024 * 512 * 4 = 8 MB)
    float* part = (float*)p; p += (size_t)4 * EE * BB * HH * 4;      // 8 MB
    float* h1   = (float*)p; p += (size_t)EE * BB * HH * 4;          // 2 MB
    float* h2   = h1;                                                 // time-shared
    float* eout = (float*)p; p += (size_t)BB * EE * DZ * 4;          // 524 KB

    hipMemsetAsync(xin, 0, (size_t)BB * EE * DD * 4, stream);

    k_weights<<<BB * NN / 256, 256, 0, stream>>>(z, a, phi, w);
    k_stats<<<BB, 256, 0, stream>>>(w, gmax, grcp);
    k_xin<<<dim3(NN / 256, BB), 192, 0, stream>>>(z, a, w, gmax, grcp, xin);

    // layer 1: 192 -> 512, split-K 2
    k_gemm<DD, HH, 96, false>
        <<<dim3(HH / 32, 2, EE), 256, 0, stream>>>(xin, W1, nullptr, part);
    k_lnact<2, true><<<EE * BB, 256, 0, stream>>>(part, b1, g1, be1, h1);

    // layer 2: 512 -> 512, split-K 4
    k_gemm<HH, HH, 128, false>
        <<<dim3(HH / 32, 4, EE), 256, 0, stream>>>(h1, W2, nullptr, part);
    k_lnact<4, true><<<EE * BB, 256, 0, stream>>>(part, b2, g2, be2, h2);

    // layer 3: 512 -> 128, split-K 8
    k_gemm<HH, DZ, 64, false>
        <<<dim3(DZ / 32, 8, EE), 256, 0, stream>>>(h2, W3, nullptr, part);
    k_fin3<8><<<EE * BB / 2, 256, 0, stream>>>(part, b3, eout);

    k_combine<<<dim3(NN / 64, BB), 256, 0, stream>>>(w, eout, out);
}